// Round 9
// baseline (255.202 us; speedup 1.0000x reference)
//
#include <hip/hip_runtime.h>
#include <hip/hip_bf16.h>
#include <math.h>

#define DIM  2048
#define NEXP 32
#define DFF  1024
#define NTOK 1024
#define TOPK 4
#define NGRP 4
#define EPG  8
#define SCALE 2.5f

#define BM 128
#define BN 128
#define BK 64
#define MAX_TILES 80
#define MAX_ROWS  10240
#define NSLOT 7                        // static: experts {0,1,2,8,16,24} + shared
#define SLOT_ELEMS (2048 * 1024)       // elements per weight matrix (2M)
#define RB 128                         // router blocks in prep (8 tokens each)
#define CONVB 2048                     // Wg/Wu conversion blocks in prep
#define DCONVB 512                     // Wd conversion blocks fused into gateup dispatch

typedef unsigned int  uint_t;
typedef unsigned short us_t;

typedef __attribute__((ext_vector_type(8))) short bf16x8;
typedef __attribute__((ext_vector_type(4))) float f32x4;

// async global->LDS, 16B per lane; LDS dst = wave-uniform base (+ lane*16 by HW)
#define GLOAD_LDS16(g, l) __builtin_amdgcn_global_load_lds( \
    (const __attribute__((address_space(1))) unsigned int*)(g), \
    (__attribute__((address_space(3))) unsigned int*)(l), 16, 0, 0)

__device__ inline us_t f2b(float f) {
  __hip_bfloat16 h = __float2bfloat16(f);   // RNE via v_cvt
  return *reinterpret_cast<const us_t*>(&h);
}

// slot -> expert id for static set {0,1,2,8,16,24}; slot 6 = shared
__device__ __host__ inline int slot_eid(int s) { return (s < 3) ? s : (s - 2) * 8; }

// ---------------- prep: fused router + x->bf16 + out-zero + Wg/Wu conversion ----------------
__global__ __launch_bounds__(256) void prep_kernel(const float* __restrict__ x,
                                                   const float* __restrict__ gw,
                                                   const float* __restrict__ bias,
                                                   const float* __restrict__ Wg,
                                                   const float* __restrict__ Wu,
                                                   const float* __restrict__ sWg,
                                                   const float* __restrict__ sWu,
                                                   us_t* __restrict__ xb,
                                                   float* __restrict__ out,
                                                   int* __restrict__ inds,
                                                   float* __restrict__ wts,
                                                   us_t* __restrict__ Wgb,
                                                   us_t* __restrict__ Wub) {
  int b = blockIdx.x, tid = threadIdx.x;
  if (b >= RB) {
    // ---- Wg/Wu conversion: 14 iterations = 2 matrices x 7 slots ----
    uint_t off = (uint_t)(b - RB) * 256 + tid;             // [0, 524288) float4 per slot
#pragma unroll
    for (int it = 0; it < 14; it++) {
      int mat = it >> 3;                                    // it 0..7 -> Wg slots, 8..13 -> Wu slots
      int slot = it & 7;
      if (it >= 7) { mat = 1; slot = it - 7; } else { mat = 0; }
      const float* sbase;
      us_t* dbase;
      if (mat == 0) { sbase = (slot < 6) ? Wg + (size_t)slot_eid(slot) * SLOT_ELEMS : sWg; dbase = Wgb; }
      else          { sbase = (slot < 6) ? Wu + (size_t)slot_eid(slot) * SLOT_ELEMS : sWu; dbase = Wub; }
      float4 v = ((const float4*)sbase)[off];
      uint2 o;
      o.x = (uint_t)f2b(v.x) | ((uint_t)f2b(v.y) << 16);
      o.y = (uint_t)f2b(v.z) | ((uint_t)f2b(v.w) << 16);
      ((uint2*)(dbase + (size_t)slot * SLOT_ELEMS))[off] = o;
    }
    return;
  }
  // ---- router: 4 waves, wave w handles tokens b*8 + w*2 .. +1 ----
  int w = tid >> 6, l = tid & 63;
  int t0 = b * 8 + w * 2;
  __shared__ float lg[4][2][NEXP];
  {
    float xa[32], xc[32];
#pragma unroll
    for (int i = 0; i < 32; i++) {
      xa[i] = x[(size_t)t0 * DIM + i * 64 + l];
      xc[i] = x[(size_t)(t0 + 1) * DIM + i * 64 + l];
    }
    for (int e = 0; e < NEXP; e++) {
      const float* wp = gw + e * DIM;
      float a0 = 0.f, a1 = 0.f;
#pragma unroll
      for (int i = 0; i < 32; i++) {
        float wv = wp[i * 64 + l];
        a0 += xa[i] * wv; a1 += xc[i] * wv;
      }
#pragma unroll
      for (int off = 32; off > 0; off >>= 1) {
        a0 += __shfl_xor(a0, off);
        a1 += __shfl_xor(a1, off);
      }
      if (l == 0) { lg[w][0][e] = a0; lg[w][1][e] = a1; }
    }
  }
  // per-wave: lanes 0,1 do selection for their token (same-wave LDS visibility)
  if (l < 2) {
    int t = t0 + l;
    float s[NEXP], sb[NEXP], mv[NEXP];
#pragma unroll
    for (int e = 0; e < NEXP; e++) {
      float sv = 1.f / (1.f + expf(-lg[w][l][e]));
      s[e] = sv; sb[e] = sv + bias[e];
    }
    float gs[NGRP];
#pragma unroll
    for (int g = 0; g < NGRP; g++) {
      float m1 = -1e30f, m2 = -1e30f;
#pragma unroll
      for (int j = 0; j < EPG; j++) {
        float v = sb[g * EPG + j];
        if (v > m1) { m2 = m1; m1 = v; } else if (v > m2) { m2 = v; }
      }
      gs[g] = m1 + m2;
    }
    int g1 = 0;
#pragma unroll
    for (int g = 1; g < NGRP; g++) if (gs[g] > gs[g1]) g1 = g;
    int g2 = -1; float g2v = -1e30f;
#pragma unroll
    for (int g = 0; g < NGRP; g++) {
      if (g == g1) continue;
      if (gs[g] > g2v) { g2v = gs[g]; g2 = g; }
    }
#pragma unroll
    for (int e = 0; e < NEXP; e++) {
      bool keep = (e == g1 * EPG) || (e == g2 * EPG);
      mv[e] = keep ? sb[e] : 0.f;
    }
    uint_t used = 0; float wsum = 0.f;
    int id[TOPK]; float wv[TOPK];
#pragma unroll
    for (int kk = 0; kk < TOPK; kk++) {
      float bv = -1e30f, bs = 0.f; int best = 0;
#pragma unroll
      for (int e = 0; e < NEXP; e++) {
        bool ok = !((used >> e) & 1u) && (mv[e] > bv);
        if (ok) { bv = mv[e]; best = e; bs = s[e]; }
      }
      used |= (1u << best);
      id[kk] = best; wv[kk] = bs; wsum += bs;
    }
    float inv = SCALE / (wsum + 1e-20f);
#pragma unroll
    for (int kk = 0; kk < TOPK; kk++) {
      inds[t * TOPK + kk] = id[kk];
      wts[t * TOPK + kk] = wv[kk] * inv;
    }
  }
  // ---- xb write + out zero for this block's 8 token rows (coalesced) ----
  {
    const float4* xr4 = (const float4*)(x + (size_t)b * 8 * DIM);   // 4096 float4
    uint2* xd = (uint2*)(xb + (size_t)b * 8 * DIM);
    float4* od = (float4*)(out + (size_t)b * 8 * DIM);
#pragma unroll
    for (int j = 0; j < 16; j++) {
      int idx = j * 256 + tid;
      float4 v = xr4[idx];
      uint2 o;
      o.x = (uint_t)f2b(v.x) | ((uint_t)f2b(v.y) << 16);
      o.y = (uint_t)f2b(v.z) | ((uint_t)f2b(v.w) << 16);
      xd[idx] = o;
      od[idx] = make_float4(0.f, 0.f, 0.f, 0.f);
    }
  }
}

// ---------------- plan: compaction over the 6 static candidate experts ----------------
__global__ __launch_bounds__(256) void plan_kernel(const int* __restrict__ inds,
                                                   const float* __restrict__ wts,
                                                   int* __restrict__ row2tok,
                                                   float* __restrict__ roww,
                                                   int* __restrict__ tileS,
                                                   int* __restrict__ tileR,
                                                   int* __restrict__ nT) {
  __shared__ int wsum[4];
  __shared__ int s_off, s_nt;
  int tid = threadIdx.x, lane = tid & 63, wv = tid >> 6;
  if (tid == 0) { s_off = 0; s_nt = 0; }
  int tb = tid * 4;
  int myi[16];
#pragma unroll
  for (int j = 0; j < 4; j++)
#pragma unroll
    for (int k = 0; k < TOPK; k++) myi[j * 4 + k] = inds[(tb + j) * TOPK + k];
  __syncthreads();
  for (int si = 0; si < 6; si++) {
    int e = slot_eid(si);
    int off0 = s_off;
    int slot[4]; int cnt = 0;
#pragma unroll
    for (int j = 0; j < 4; j++) {
      int sl = -1;
#pragma unroll
      for (int k = 0; k < TOPK; k++) if (myi[j * 4 + k] == e) sl = k;
      slot[j] = sl; cnt += (sl >= 0) ? 1 : 0;
    }
    int v = cnt;
#pragma unroll
    for (int off = 1; off < 64; off <<= 1) {
      int u = __shfl_up(v, (unsigned)off);
      if (lane >= off) v += u;
    }
    if (lane == 63) wsum[wv] = v;
    __syncthreads();
    int base = 0;
#pragma unroll
    for (int w = 0; w < 4; w++) base += (w < wv) ? wsum[w] : 0;
    int total = wsum[0] + wsum[1] + wsum[2] + wsum[3];
    int r = off0 + base + v - cnt;
#pragma unroll
    for (int j = 0; j < 4; j++) {
      if (slot[j] >= 0) {
        int t = tb + j;
        row2tok[r] = t; roww[r] = wts[t * TOPK + slot[j]];
        r++;
      }
    }
    int ntm = (total + BM - 1) / BM;
    int padEnd = off0 + ntm * BM;
    for (int q = off0 + total + tid; q < padEnd; q += 256) { row2tok[q] = 0; roww[q] = 0.f; }
    __syncthreads();
    if (tid == 0) {
      for (int i = 0; i < ntm; i++) { tileS[s_nt + i] = si; tileR[s_nt + i] = off0 + i * BM; }
      s_nt += ntm; s_off = padEnd;
    }
    __syncthreads();
  }
  int off0 = s_off;
  for (int t = tid; t < NTOK; t += 256) { row2tok[off0 + t] = t; roww[off0 + t] = 1.f; }
  if (tid == 0) {
    for (int i = 0; i < NTOK / BM; i++) { tileS[s_nt + i] = 6; tileR[s_nt + i] = off0 + i * BM; }
    nT[0] = s_nt + NTOK / BM;
  }
}

// ---------------- gate/up GEMM + fused Wd conversion blocks ----------------
__global__ __launch_bounds__(512) void gateup_kernel(const us_t* __restrict__ xb,
                                                     const us_t* __restrict__ Wgb,
                                                     const us_t* __restrict__ Wub,
                                                     const float* __restrict__ Wd,
                                                     const float* __restrict__ sWd,
                                                     us_t* __restrict__ Wdb,
                                                     const int* __restrict__ row2tok,
                                                     const int* __restrict__ tileS,
                                                     const int* __restrict__ tileR,
                                                     const int* __restrict__ nT,
                                                     us_t* __restrict__ H) {
  int bidx = blockIdx.x;
  if (bidx < DCONVB) {
    // ---- Wd conversion: 7 slots x 2 chunks of 262144 float4 ----
    int tid = threadIdx.x;
    uint_t base = (uint_t)bidx * 512 + tid;                 // [0, 262144)
#pragma unroll
    for (int slot = 0; slot < 7; slot++) {
      const float* sbase = (slot < 6) ? Wd + (size_t)slot_eid(slot) * SLOT_ELEMS : sWd;
      uint2* dbase = (uint2*)(Wdb + (size_t)slot * SLOT_ELEMS);
#pragma unroll
      for (int j = 0; j < 2; j++) {
        uint_t off = base + (uint_t)j * 262144;
        float4 v = ((const float4*)sbase)[off];
        uint2 o;
        o.x = (uint_t)f2b(v.x) | ((uint_t)f2b(v.y) << 16);
        o.y = (uint_t)f2b(v.z) | ((uint_t)f2b(v.w) << 16);
        dbase[off] = o;
      }
    }
    return;
  }
  int hw = bidx - DCONVB;                                  // 640 blocks, 640%8==0
  int work = (hw & 7) * (MAX_TILES * (DFF / BN) / 8) + (hw >> 3);
  int tile = work % MAX_TILES;
  int n0 = (work / MAX_TILES) * BN;
  if (tile >= nT[0]) return;
  int sl = tileS[tile], row0 = tileR[tile];
  const us_t* wgp = Wgb + (size_t)sl * SLOT_ELEMS;
  const us_t* wup = Wub + (size_t)sl * SLOT_ELEMS;

  __shared__ us_t Xs[BM][BK];   // 16 KB each, content swizzled:
  __shared__ us_t Gs[BN][BK];   //   slot(r,cc) holds source chunk (r, cc^(r&7))
  __shared__ us_t Us[BN][BK];

  int tid = threadIdx.x;
  int lane = tid & 63;
  int wid = tid >> 6;
  int wmr = (wid >> 2) * 64;
  int wnc = (wid & 3) * 32;

  // staging: 1024 16B-slots per panel; wave w covers slots [w*128, w*128+128)
  int s0 = wid * 128 + lane, s1 = s0 + 64;
  int r0 = s0 >> 3, c0 = s0 & 7;
  int r1 = s1 >> 3, c1 = s1 & 7;
  const us_t* xsrc0 = xb + (size_t)row2tok[row0 + r0] * DIM + (c0 ^ (r0 & 7)) * 8;
  const us_t* xsrc1 = xb + (size_t)row2tok[row0 + r1] * DIM + (c1 ^ (r1 & 7)) * 8;
  const us_t* gsrc0 = wgp + (size_t)(n0 + r0) * DIM + (c0 ^ (r0 & 7)) * 8;
  const us_t* gsrc1 = wgp + (size_t)(n0 + r1) * DIM + (c1 ^ (r1 & 7)) * 8;
  const us_t* usrc0 = wup + (size_t)(n0 + r0) * DIM + (c0 ^ (r0 & 7)) * 8;
  const us_t* usrc1 = wup + (size_t)(n0 + r1) * DIM + (c1 ^ (r1 & 7)) * 8;
  size_t do0 = (size_t)(wid * 128) * 8;   // wave-uniform dst offset (us_t units)
  size_t do1 = do0 + 64 * 8;

  f32x4 accg[4][2] = {};
  f32x4 accu[4][2] = {};

  for (int kt = 0; kt < DIM; kt += BK) {
    GLOAD_LDS16(xsrc0 + kt, &Xs[0][0] + do0);
    GLOAD_LDS16(xsrc1 + kt, &Xs[0][0] + do1);
    GLOAD_LDS16(gsrc0 + kt, &Gs[0][0] + do0);
    GLOAD_LDS16(gsrc1 + kt, &Gs[0][0] + do1);
    GLOAD_LDS16(usrc0 + kt, &Us[0][0] + do0);
    GLOAD_LDS16(usrc1 + kt, &Us[0][0] + do1);
    __syncthreads();
#pragma unroll
    for (int ks = 0; ks < BK; ks += 32) {
      int cb = (ks >> 3) + (lane >> 4);
      bf16x8 af[4], bg[2], bu[2];
#pragma unroll
      for (int mi = 0; mi < 4; mi++) {
        int r = wmr + mi * 16 + (lane & 15);
        af[mi] = *(const bf16x8*)&(((const uint4*)&Xs[r][0])[cb ^ (r & 7)]);
      }
#pragma unroll
      for (int ni = 0; ni < 2; ni++) {
        int r = wnc + ni * 16 + (lane & 15);
        bg[ni] = *(const bf16x8*)&(((const uint4*)&Gs[r][0])[cb ^ (r & 7)]);
        bu[ni] = *(const bf16x8*)&(((const uint4*)&Us[r][0])[cb ^ (r & 7)]);
      }
#pragma unroll
      for (int mi = 0; mi < 4; mi++)
#pragma unroll
        for (int ni = 0; ni < 2; ni++) {
          accg[mi][ni] = __builtin_amdgcn_mfma_f32_16x16x32_bf16(af[mi], bg[ni], accg[mi][ni], 0, 0, 0);
          accu[mi][ni] = __builtin_amdgcn_mfma_f32_16x16x32_bf16(af[mi], bu[ni], accu[mi][ni], 0, 0, 0);
        }
    }
    __syncthreads();
  }
#pragma unroll
  for (int mi = 0; mi < 4; mi++) {
#pragma unroll
    for (int j = 0; j < 4; j++) {
      int r = row0 + wmr + mi * 16 + (lane >> 4) * 4 + j;
      us_t* hrow = H + (size_t)r * DFF;
#pragma unroll
      for (int ni = 0; ni < 2; ni++) {
        float g = accg[mi][ni][j], u = accu[mi][ni][j];
        float h = (g / (1.f + expf(-g))) * u;
        hrow[n0 + wnc + ni * 16 + (lane & 15)] = f2b(h);
      }
    }
  }
}

// ---------------- down GEMM + weighted scatter-add ----------------
__global__ __launch_bounds__(512) void down_kernel(const us_t* __restrict__ H,
                                                   const us_t* __restrict__ Wdb,
                                                   const int* __restrict__ row2tok,
                                                   const float* __restrict__ roww,
                                                   const int* __restrict__ tileS,
                                                   const int* __restrict__ tileR,
                                                   const int* __restrict__ nT,
                                                   float* __restrict__ out) {
  int hw = blockIdx.x;                                   // 1280 blocks
  int work = (hw & 7) * (MAX_TILES * (DIM / BN) / 8) + (hw >> 3);
  int tile = work % MAX_TILES;
  int n0 = (work / MAX_TILES) * BN;
  if (tile >= nT[0]) return;
  int sl = tileS[tile], row0 = tileR[tile];
  const us_t* wd = Wdb + (size_t)sl * SLOT_ELEMS;

  __shared__ us_t Hs[BM][BK];   // 16 KB
  __shared__ us_t Ds[BN][BK];   // 16 KB

  int tid = threadIdx.x;
  int lane = tid & 63;
  int wid = tid >> 6;
  int wmr = (wid >> 2) * 64;
  int wnc = (wid & 3) * 32;

  int s0 = wid * 128 + lane, s1 = s0 + 64;
  int r0 = s0 >> 3, c0 = s0 & 7;
  int r1 = s1 >> 3, c1 = s1 & 7;
  const us_t* hsrc0 = H + (size_t)(row0 + r0) * DFF + (c0 ^ (r0 & 7)) * 8;
  const us_t* hsrc1 = H + (size_t)(row0 + r1) * DFF + (c1 ^ (r1 & 7)) * 8;
  const us_t* dsrc0 = wd + (size_t)(n0 + r0) * DFF + (c0 ^ (r0 & 7)) * 8;
  const us_t* dsrc1 = wd + (size_t)(n0 + r1) * DFF + (c1 ^ (r1 & 7)) * 8;
  size_t do0 = (size_t)(wid * 128) * 8;
  size_t do1 = do0 + 64 * 8;

  f32x4 acc[4][2] = {};

  for (int kt = 0; kt < DFF; kt += BK) {
    GLOAD_LDS16(hsrc0 + kt, &Hs[0][0] + do0);
    GLOAD_LDS16(hsrc1 + kt, &Hs[0][0] + do1);
    GLOAD_LDS16(dsrc0 + kt, &Ds[0][0] + do0);
    GLOAD_LDS16(dsrc1 + kt, &Ds[0][0] + do1);
    __syncthreads();
#pragma unroll
    for (int ks = 0; ks < BK; ks += 32) {
      int cb = (ks >> 3) + (lane >> 4);
      bf16x8 af[4], bw[2];
#pragma unroll
      for (int mi = 0; mi < 4; mi++) {
        int r = wmr + mi * 16 + (lane & 15);
        af[mi] = *(const bf16x8*)&(((const uint4*)&Hs[r][0])[cb ^ (r & 7)]);
      }
#pragma unroll
      for (int ni = 0; ni < 2; ni++) {
        int r = wnc + ni * 16 + (lane & 15);
        bw[ni] = *(const bf16x8*)&(((const uint4*)&Ds[r][0])[cb ^ (r & 7)]);
      }
#pragma unroll
      for (int mi = 0; mi < 4; mi++)
#pragma unroll
        for (int ni = 0; ni < 2; ni++)
          acc[mi][ni] = __builtin_amdgcn_mfma_f32_16x16x32_bf16(af[mi], bw[ni], acc[mi][ni], 0, 0, 0);
    }
    __syncthreads();
  }
#pragma unroll
  for (int mi = 0; mi < 4; mi++) {
#pragma unroll
    for (int j = 0; j < 4; j++) {
      int r = row0 + wmr + mi * 16 + (lane >> 4) * 4 + j;
      float wgt = roww[r];
      int tok = row2tok[r];
      float* orow = out + (size_t)tok * DIM;
#pragma unroll
      for (int ni = 0; ni < 2; ni++)
        atomicAdd(orow + n0 + wnc + ni * 16 + (lane & 15), acc[mi][ni][j] * wgt);
    }
  }
}

extern "C" void kernel_launch(void* const* d_in, const int* in_sizes, int n_in,
                              void* d_out, int out_size, void* d_ws, size_t ws_size,
                              hipStream_t stream) {
  const float* x    = (const float*)d_in[0];
  const float* gw   = (const float*)d_in[1];
  const float* bias = (const float*)d_in[2];
  const float* Wg   = (const float*)d_in[3];
  const float* Wu   = (const float*)d_in[4];
  const float* Wd   = (const float*)d_in[5];
  const float* sWg  = (const float*)d_in[6];
  const float* sWu  = (const float*)d_in[7];
  const float* sWd  = (const float*)d_in[8];
  float* out = (float*)d_out;

  char* p = (char*)d_ws;
  us_t* xb  = (us_t*)p;           p += (size_t)NTOK * DIM * 2;
  us_t* H   = (us_t*)p;           p += (size_t)MAX_ROWS * DFF * 2;
  us_t* Wgb = (us_t*)p;           p += (size_t)NSLOT * SLOT_ELEMS * 2;
  us_t* Wub = (us_t*)p;           p += (size_t)NSLOT * SLOT_ELEMS * 2;
  us_t* Wdb = (us_t*)p;           p += (size_t)NSLOT * SLOT_ELEMS * 2;
  int* inds = (int*)p;            p += NTOK * TOPK * 4;
  float* wts = (float*)p;         p += NTOK * TOPK * 4;
  int* row2tok = (int*)p;         p += MAX_ROWS * 4;
  float* roww = (float*)p;        p += MAX_ROWS * 4;
  int* tileS = (int*)p;           p += MAX_TILES * 4;
  int* tileR = (int*)p;           p += MAX_TILES * 4;
  int* nT = (int*)p;              p += 4;

  hipLaunchKernelGGL(prep_kernel, dim3(RB + CONVB), dim3(256), 0, stream,
                     x, gw, bias, Wg, Wu, sWg, sWu,
                     xb, out, inds, wts, Wgb, Wub);
  hipLaunchKernelGGL(plan_kernel, dim3(1), dim3(256), 0, stream,
                     inds, wts, row2tok, roww, tileS, tileR, nT);
  hipLaunchKernelGGL(gateup_kernel, dim3(DCONVB + MAX_TILES * (DFF / BN)), dim3(512), 0, stream,
                     xb, Wgb, Wub, Wd, sWd, Wdb, row2tok, tileS, tileR, nT, H);
  hipLaunchKernelGGL(down_kernel, dim3(MAX_TILES * (DIM / BN)), dim3(512), 0, stream,
                     H, Wdb, row2tok, roww, tileS, tileR, nT, out);
}

// Round 10
// 212.902 us; speedup vs baseline: 1.1987x; 1.1987x over previous
//
#include <hip/hip_runtime.h>
#include <hip/hip_bf16.h>
#include <math.h>

#define DIM  2048
#define NEXP 32
#define DFF  1024
#define NTOK 1024
#define TOPK 4
#define NGRP 4
#define EPG  8
#define SCALE 2.5f

#define BM 128
#define BN 128
#define BK 64
#define MAX_TILES 80
#define MAX_ROWS  10240
#define NSLOT 7                        // static: experts {0,1,2,8,16,24} + shared
#define SLOT_ELEMS (2048 * 1024)       // elements per weight matrix (2M)
#define RB 128                         // router blocks in prep (8 tokens each)
#define CONVB 2048                     // conversion blocks in prep

typedef unsigned int  uint_t;
typedef unsigned short us_t;

typedef __attribute__((ext_vector_type(8))) short bf16x8;
typedef __attribute__((ext_vector_type(4))) float f32x4;

// async global->LDS, 16B per lane; LDS dst = wave-uniform base (+ lane*16 by HW)
#define GLOAD_LDS16(g, l) __builtin_amdgcn_global_load_lds( \
    (const __attribute__((address_space(1))) unsigned int*)(g), \
    (__attribute__((address_space(3))) unsigned int*)(l), 16, 0, 0)

__device__ inline us_t f2b(float f) {
  __hip_bfloat16 h = __float2bfloat16(f);   // RNE via v_cvt
  return *reinterpret_cast<const us_t*>(&h);
}

// slot -> expert id for static set {0,1,2,8,16,24}; slot 6 = shared
__device__ __host__ inline int slot_eid(int s) { return (s < 3) ? s : (s - 2) * 8; }

// ---------------- prep: fused router + x->bf16 + out-zero + full weight conversion ----------------
__global__ __launch_bounds__(256) void prep_kernel(const float* __restrict__ x,
                                                   const float* __restrict__ gw,
                                                   const float* __restrict__ bias,
                                                   const float* __restrict__ Wg,
                                                   const float* __restrict__ Wu,
                                                   const float* __restrict__ Wd,
                                                   const float* __restrict__ sWg,
                                                   const float* __restrict__ sWu,
                                                   const float* __restrict__ sWd,
                                                   us_t* __restrict__ xb,
                                                   float* __restrict__ out,
                                                   int* __restrict__ inds,
                                                   float* __restrict__ wts,
                                                   us_t* __restrict__ Wgb,
                                                   us_t* __restrict__ Wub,
                                                   us_t* __restrict__ Wdb) {
  int b = blockIdx.x, tid = threadIdx.x;
  if (b >= RB) {
    // ---- weight conversion: 21 iterations = 3 matrices x 7 slots ----
    uint_t off = (uint_t)(b - RB) * 256 + tid;             // [0, 524288) float4 per slot
#pragma unroll
    for (int it = 0; it < 21; it++) {
      int mat = it / 7, slot = it % 7;                     // constant-folded per iteration
      const float* sbase;
      us_t* dbase;
      if (mat == 0)      { sbase = (slot < 6) ? Wg + (size_t)slot_eid(slot) * SLOT_ELEMS : sWg; dbase = Wgb; }
      else if (mat == 1) { sbase = (slot < 6) ? Wu + (size_t)slot_eid(slot) * SLOT_ELEMS : sWu; dbase = Wub; }
      else               { sbase = (slot < 6) ? Wd + (size_t)slot_eid(slot) * SLOT_ELEMS : sWd; dbase = Wdb; }
      float4 v = ((const float4*)sbase)[off];
      uint2 o;
      o.x = (uint_t)f2b(v.x) | ((uint_t)f2b(v.y) << 16);
      o.y = (uint_t)f2b(v.z) | ((uint_t)f2b(v.w) << 16);
      ((uint2*)(dbase + (size_t)slot * SLOT_ELEMS))[off] = o;
    }
    return;
  }
  // ---- router: 4 waves, wave w handles tokens b*8 + w*2 .. +1 ----
  int w = tid >> 6, l = tid & 63;
  int t0 = b * 8 + w * 2;
  __shared__ float lg[4][2][NEXP];
  {
    float xa[32], xc[32];
#pragma unroll
    for (int i = 0; i < 32; i++) {
      xa[i] = x[(size_t)t0 * DIM + i * 64 + l];
      xc[i] = x[(size_t)(t0 + 1) * DIM + i * 64 + l];
    }
    for (int e = 0; e < NEXP; e++) {
      const float* wp = gw + e * DIM;
      float a0 = 0.f, a1 = 0.f;
#pragma unroll
      for (int i = 0; i < 32; i++) {
        float wv = wp[i * 64 + l];
        a0 += xa[i] * wv; a1 += xc[i] * wv;
      }
#pragma unroll
      for (int off = 32; off > 0; off >>= 1) {
        a0 += __shfl_xor(a0, off);
        a1 += __shfl_xor(a1, off);
      }
      if (l == 0) { lg[w][0][e] = a0; lg[w][1][e] = a1; }
    }
  }
  // per-wave: lanes 0,1 do selection for their token (same-wave LDS visibility)
  if (l < 2) {
    int t = t0 + l;
    float s[NEXP], sb[NEXP], mv[NEXP];
#pragma unroll
    for (int e = 0; e < NEXP; e++) {
      float sv = 1.f / (1.f + expf(-lg[w][l][e]));
      s[e] = sv; sb[e] = sv + bias[e];
    }
    float gs[NGRP];
#pragma unroll
    for (int g = 0; g < NGRP; g++) {
      float m1 = -1e30f, m2 = -1e30f;
#pragma unroll
      for (int j = 0; j < EPG; j++) {
        float v = sb[g * EPG + j];
        if (v > m1) { m2 = m1; m1 = v; } else if (v > m2) { m2 = v; }
      }
      gs[g] = m1 + m2;
    }
    int g1 = 0;
#pragma unroll
    for (int g = 1; g < NGRP; g++) if (gs[g] > gs[g1]) g1 = g;
    int g2 = -1; float g2v = -1e30f;
#pragma unroll
    for (int g = 0; g < NGRP; g++) {
      if (g == g1) continue;
      if (gs[g] > g2v) { g2v = gs[g]; g2 = g; }
    }
#pragma unroll
    for (int e = 0; e < NEXP; e++) {
      bool keep = (e == g1 * EPG) || (e == g2 * EPG);
      mv[e] = keep ? sb[e] : 0.f;
    }
    uint_t used = 0; float wsum = 0.f;
    int id[TOPK]; float wv[TOPK];
#pragma unroll
    for (int kk = 0; kk < TOPK; kk++) {
      float bv = -1e30f, bs = 0.f; int best = 0;
#pragma unroll
      for (int e = 0; e < NEXP; e++) {
        bool ok = !((used >> e) & 1u) && (mv[e] > bv);
        if (ok) { bv = mv[e]; best = e; bs = s[e]; }
      }
      used |= (1u << best);
      id[kk] = best; wv[kk] = bs; wsum += bs;
    }
    float inv = SCALE / (wsum + 1e-20f);
#pragma unroll
    for (int kk = 0; kk < TOPK; kk++) {
      inds[t * TOPK + kk] = id[kk];
      wts[t * TOPK + kk] = wv[kk] * inv;
    }
  }
  // ---- xb write + out zero for this block's 8 token rows (coalesced) ----
  {
    const float4* xr4 = (const float4*)(x + (size_t)b * 8 * DIM);   // 4096 float4
    uint2* xd = (uint2*)(xb + (size_t)b * 8 * DIM);
    float4* od = (float4*)(out + (size_t)b * 8 * DIM);
#pragma unroll
    for (int j = 0; j < 16; j++) {
      int idx = j * 256 + tid;
      float4 v = xr4[idx];
      uint2 o;
      o.x = (uint_t)f2b(v.x) | ((uint_t)f2b(v.y) << 16);
      o.y = (uint_t)f2b(v.z) | ((uint_t)f2b(v.w) << 16);
      xd[idx] = o;
      od[idx] = make_float4(0.f, 0.f, 0.f, 0.f);
    }
  }
}

// ---------------- plan: compaction over the 6 static candidate experts ----------------
__global__ __launch_bounds__(256) void plan_kernel(const int* __restrict__ inds,
                                                   const float* __restrict__ wts,
                                                   int* __restrict__ row2tok,
                                                   float* __restrict__ roww,
                                                   int* __restrict__ tileS,
                                                   int* __restrict__ tileR,
                                                   int* __restrict__ nT) {
  __shared__ int wsum[4];
  __shared__ int s_off, s_nt;
  int tid = threadIdx.x, lane = tid & 63, wv = tid >> 6;
  if (tid == 0) { s_off = 0; s_nt = 0; }
  int tb = tid * 4;
  int myi[16];
#pragma unroll
  for (int j = 0; j < 4; j++)
#pragma unroll
    for (int k = 0; k < TOPK; k++) myi[j * 4 + k] = inds[(tb + j) * TOPK + k];
  __syncthreads();
  for (int si = 0; si < 6; si++) {
    int e = slot_eid(si);
    int off0 = s_off;
    int slot[4]; int cnt = 0;
#pragma unroll
    for (int j = 0; j < 4; j++) {
      int sl = -1;
#pragma unroll
      for (int k = 0; k < TOPK; k++) if (myi[j * 4 + k] == e) sl = k;
      slot[j] = sl; cnt += (sl >= 0) ? 1 : 0;
    }
    int v = cnt;
#pragma unroll
    for (int off = 1; off < 64; off <<= 1) {
      int u = __shfl_up(v, (unsigned)off);
      if (lane >= off) v += u;
    }
    if (lane == 63) wsum[wv] = v;
    __syncthreads();
    int base = 0;
#pragma unroll
    for (int w = 0; w < 4; w++) base += (w < wv) ? wsum[w] : 0;
    int total = wsum[0] + wsum[1] + wsum[2] + wsum[3];
    int r = off0 + base + v - cnt;
#pragma unroll
    for (int j = 0; j < 4; j++) {
      if (slot[j] >= 0) {
        int t = tb + j;
        row2tok[r] = t; roww[r] = wts[t * TOPK + slot[j]];
        r++;
      }
    }
    int ntm = (total + BM - 1) / BM;
    int padEnd = off0 + ntm * BM;
    for (int q = off0 + total + tid; q < padEnd; q += 256) { row2tok[q] = 0; roww[q] = 0.f; }
    __syncthreads();
    if (tid == 0) {
      for (int i = 0; i < ntm; i++) { tileS[s_nt + i] = si; tileR[s_nt + i] = off0 + i * BM; }
      s_nt += ntm; s_off = padEnd;
    }
    __syncthreads();
  }
  int off0 = s_off;
  for (int t = tid; t < NTOK; t += 256) { row2tok[off0 + t] = t; roww[off0 + t] = 1.f; }
  if (tid == 0) {
    for (int i = 0; i < NTOK / BM; i++) { tileS[s_nt + i] = 6; tileR[s_nt + i] = off0 + i * BM; }
    nT[0] = s_nt + NTOK / BM;
  }
}

// ---------------- gate/up GEMM: 128x128, all panels via global_load_lds ----------------
__global__ __launch_bounds__(512) void gateup_kernel(const us_t* __restrict__ xb,
                                                     const us_t* __restrict__ Wgb,
                                                     const us_t* __restrict__ Wub,
                                                     const int* __restrict__ row2tok,
                                                     const int* __restrict__ tileS,
                                                     const int* __restrict__ tileR,
                                                     const int* __restrict__ nT,
                                                     us_t* __restrict__ H) {
  int hw = blockIdx.x;                                   // 640 blocks, 640%8==0
  int work = (hw & 7) * (MAX_TILES * (DFF / BN) / 8) + (hw >> 3);
  int tile = work % MAX_TILES;
  int n0 = (work / MAX_TILES) * BN;
  if (tile >= nT[0]) return;
  int sl = tileS[tile], row0 = tileR[tile];
  const us_t* wgp = Wgb + (size_t)sl * SLOT_ELEMS;
  const us_t* wup = Wub + (size_t)sl * SLOT_ELEMS;

  __shared__ us_t Xs[BM][BK];   // 16 KB each, content swizzled:
  __shared__ us_t Gs[BN][BK];   //   slot(r,cc) holds source chunk (r, cc^(r&7))
  __shared__ us_t Us[BN][BK];

  int tid = threadIdx.x;
  int lane = tid & 63;
  int wid = tid >> 6;
  int wmr = (wid >> 2) * 64;
  int wnc = (wid & 3) * 32;

  // staging: 1024 16B-slots per panel; wave w covers slots [w*128, w*128+128)
  int s0 = wid * 128 + lane, s1 = s0 + 64;
  int r0 = s0 >> 3, c0 = s0 & 7;
  int r1 = s1 >> 3, c1 = s1 & 7;
  const us_t* xsrc0 = xb + (size_t)row2tok[row0 + r0] * DIM + (c0 ^ (r0 & 7)) * 8;
  const us_t* xsrc1 = xb + (size_t)row2tok[row0 + r1] * DIM + (c1 ^ (r1 & 7)) * 8;
  const us_t* gsrc0 = wgp + (size_t)(n0 + r0) * DIM + (c0 ^ (r0 & 7)) * 8;
  const us_t* gsrc1 = wgp + (size_t)(n0 + r1) * DIM + (c1 ^ (r1 & 7)) * 8;
  const us_t* usrc0 = wup + (size_t)(n0 + r0) * DIM + (c0 ^ (r0 & 7)) * 8;
  const us_t* usrc1 = wup + (size_t)(n0 + r1) * DIM + (c1 ^ (r1 & 7)) * 8;
  size_t do0 = (size_t)(wid * 128) * 8;   // wave-uniform dst offset (us_t units)
  size_t do1 = do0 + 64 * 8;

  f32x4 accg[4][2] = {};
  f32x4 accu[4][2] = {};

  for (int kt = 0; kt < DIM; kt += BK) {
    GLOAD_LDS16(xsrc0 + kt, &Xs[0][0] + do0);
    GLOAD_LDS16(xsrc1 + kt, &Xs[0][0] + do1);
    GLOAD_LDS16(gsrc0 + kt, &Gs[0][0] + do0);
    GLOAD_LDS16(gsrc1 + kt, &Gs[0][0] + do1);
    GLOAD_LDS16(usrc0 + kt, &Us[0][0] + do0);
    GLOAD_LDS16(usrc1 + kt, &Us[0][0] + do1);
    __syncthreads();
#pragma unroll
    for (int ks = 0; ks < BK; ks += 32) {
      int cb = (ks >> 3) + (lane >> 4);
      bf16x8 af[4], bg[2], bu[2];
#pragma unroll
      for (int mi = 0; mi < 4; mi++) {
        int r = wmr + mi * 16 + (lane & 15);
        af[mi] = *(const bf16x8*)&(((const uint4*)&Xs[r][0])[cb ^ (r & 7)]);
      }
#pragma unroll
      for (int ni = 0; ni < 2; ni++) {
        int r = wnc + ni * 16 + (lane & 15);
        bg[ni] = *(const bf16x8*)&(((const uint4*)&Gs[r][0])[cb ^ (r & 7)]);
        bu[ni] = *(const bf16x8*)&(((const uint4*)&Us[r][0])[cb ^ (r & 7)]);
      }
#pragma unroll
      for (int mi = 0; mi < 4; mi++)
#pragma unroll
        for (int ni = 0; ni < 2; ni++) {
          accg[mi][ni] = __builtin_amdgcn_mfma_f32_16x16x32_bf16(af[mi], bg[ni], accg[mi][ni], 0, 0, 0);
          accu[mi][ni] = __builtin_amdgcn_mfma_f32_16x16x32_bf16(af[mi], bu[ni], accu[mi][ni], 0, 0, 0);
        }
    }
    __syncthreads();
  }
#pragma unroll
  for (int mi = 0; mi < 4; mi++) {
#pragma unroll
    for (int j = 0; j < 4; j++) {
      int r = row0 + wmr + mi * 16 + (lane >> 4) * 4 + j;
      us_t* hrow = H + (size_t)r * DFF;
#pragma unroll
      for (int ni = 0; ni < 2; ni++) {
        float g = accg[mi][ni][j], u = accu[mi][ni][j];
        float h = (g / (1.f + expf(-g))) * u;
        hrow[n0 + wnc + ni * 16 + (lane & 15)] = f2b(h);
      }
    }
  }
}

// ---------------- down GEMM + weighted scatter-add ----------------
__global__ __launch_bounds__(512) void down_kernel(const us_t* __restrict__ H,
                                                   const us_t* __restrict__ Wdb,
                                                   const int* __restrict__ row2tok,
                                                   const float* __restrict__ roww,
                                                   const int* __restrict__ tileS,
                                                   const int* __restrict__ tileR,
                                                   const int* __restrict__ nT,
                                                   float* __restrict__ out) {
  int hw = blockIdx.x;                                   // 1280 blocks
  int work = (hw & 7) * (MAX_TILES * (DIM / BN) / 8) + (hw >> 3);
  int tile = work % MAX_TILES;
  int n0 = (work / MAX_TILES) * BN;
  if (tile >= nT[0]) return;
  int sl = tileS[tile], row0 = tileR[tile];
  const us_t* wd = Wdb + (size_t)sl * SLOT_ELEMS;

  __shared__ us_t Hs[BM][BK];   // 16 KB
  __shared__ us_t Ds[BN][BK];   // 16 KB

  int tid = threadIdx.x;
  int lane = tid & 63;
  int wid = tid >> 6;
  int wmr = (wid >> 2) * 64;
  int wnc = (wid & 3) * 32;

  int s0 = wid * 128 + lane, s1 = s0 + 64;
  int r0 = s0 >> 3, c0 = s0 & 7;
  int r1 = s1 >> 3, c1 = s1 & 7;
  const us_t* hsrc0 = H + (size_t)(row0 + r0) * DFF + (c0 ^ (r0 & 7)) * 8;
  const us_t* hsrc1 = H + (size_t)(row0 + r1) * DFF + (c1 ^ (r1 & 7)) * 8;
  const us_t* dsrc0 = wd + (size_t)(n0 + r0) * DFF + (c0 ^ (r0 & 7)) * 8;
  const us_t* dsrc1 = wd + (size_t)(n0 + r1) * DFF + (c1 ^ (r1 & 7)) * 8;
  size_t do0 = (size_t)(wid * 128) * 8;
  size_t do1 = do0 + 64 * 8;

  f32x4 acc[4][2] = {};

  for (int kt = 0; kt < DFF; kt += BK) {
    GLOAD_LDS16(hsrc0 + kt, &Hs[0][0] + do0);
    GLOAD_LDS16(hsrc1 + kt, &Hs[0][0] + do1);
    GLOAD_LDS16(dsrc0 + kt, &Ds[0][0] + do0);
    GLOAD_LDS16(dsrc1 + kt, &Ds[0][0] + do1);
    __syncthreads();
#pragma unroll
    for (int ks = 0; ks < BK; ks += 32) {
      int cb = (ks >> 3) + (lane >> 4);
      bf16x8 af[4], bw[2];
#pragma unroll
      for (int mi = 0; mi < 4; mi++) {
        int r = wmr + mi * 16 + (lane & 15);
        af[mi] = *(const bf16x8*)&(((const uint4*)&Hs[r][0])[cb ^ (r & 7)]);
      }
#pragma unroll
      for (int ni = 0; ni < 2; ni++) {
        int r = wnc + ni * 16 + (lane & 15);
        bw[ni] = *(const bf16x8*)&(((const uint4*)&Ds[r][0])[cb ^ (r & 7)]);
      }
#pragma unroll
      for (int mi = 0; mi < 4; mi++)
#pragma unroll
        for (int ni = 0; ni < 2; ni++)
          acc[mi][ni] = __builtin_amdgcn_mfma_f32_16x16x32_bf16(af[mi], bw[ni], acc[mi][ni], 0, 0, 0);
    }
    __syncthreads();
  }
#pragma unroll
  for (int mi = 0; mi < 4; mi++) {
#pragma unroll
    for (int j = 0; j < 4; j++) {
      int r = row0 + wmr + mi * 16 + (lane >> 4) * 4 + j;
      float wgt = roww[r];
      int tok = row2tok[r];
      float* orow = out + (size_t)tok * DIM;
#pragma unroll
      for (int ni = 0; ni < 2; ni++)
        atomicAdd(orow + n0 + wnc + ni * 16 + (lane & 15), acc[mi][ni][j] * wgt);
    }
  }
}

extern "C" void kernel_launch(void* const* d_in, const int* in_sizes, int n_in,
                              void* d_out, int out_size, void* d_ws, size_t ws_size,
                              hipStream_t stream) {
  const float* x    = (const float*)d_in[0];
  const float* gw   = (const float*)d_in[1];
  const float* bias = (const float*)d_in[2];
  const float* Wg   = (const float*)d_in[3];
  const float* Wu   = (const float*)d_in[4];
  const float* Wd   = (const float*)d_in[5];
  const float* sWg  = (const float*)d_in[6];
  const float* sWu  = (const float*)d_in[7];
  const float* sWd  = (const float*)d_in[8];
  float* out = (float*)d_out;

  char* p = (char*)d_ws;
  us_t* xb  = (us_t*)p;           p += (size_t)NTOK * DIM * 2;
  us_t* H   = (us_t*)p;           p += (size_t)MAX_ROWS * DFF * 2;
  us_t* Wgb = (us_t*)p;           p += (size_t)NSLOT * SLOT_ELEMS * 2;
  us_t* Wub = (us_t*)p;           p += (size_t)NSLOT * SLOT_ELEMS * 2;
  us_t* Wdb = (us_t*)p;           p += (size_t)NSLOT * SLOT_ELEMS * 2;
  int* inds = (int*)p;            p += NTOK * TOPK * 4;
  float* wts = (float*)p;         p += NTOK * TOPK * 4;
  int* row2tok = (int*)p;         p += MAX_ROWS * 4;
  float* roww = (float*)p;        p += MAX_ROWS * 4;
  int* tileS = (int*)p;           p += MAX_TILES * 4;
  int* tileR = (int*)p;           p += MAX_TILES * 4;
  int* nT = (int*)p;              p += 4;

  hipLaunchKernelGGL(prep_kernel, dim3(RB + CONVB), dim3(256), 0, stream,
                     x, gw, bias, Wg, Wu, Wd, sWg, sWu, sWd,
                     xb, out, inds, wts, Wgb, Wub, Wdb);
  hipLaunchKernelGGL(plan_kernel, dim3(1), dim3(256), 0, stream,
                     inds, wts, row2tok, roww, tileS, tileR, nT);
  hipLaunchKernelGGL(gateup_kernel, dim3(MAX_TILES * (DFF / BN)), dim3(512), 0, stream,
                     xb, Wgb, Wub, row2tok, tileS, tileR, nT, H);
  hipLaunchKernelGGL(down_kernel, dim3(MAX_TILES * (DIM / BN)), dim3(512), 0, stream,
                     H, Wdb, row2tok, roww, tileS, tileR, nT, out);
}